// Round 7
// baseline (337.162 us; speedup 1.0000x reference)
//
#include <hip/hip_runtime.h>
#include <math.h>

#define T_LEN 8192
#define NS_G 8   // gram K-slices

typedef float  f32x4 __attribute__((ext_vector_type(4)));
typedef _Float16 f16x8 __attribute__((ext_vector_type(8)));

__device__ __forceinline__ constexpr int br5(int r) {
    return ((r & 1) << 4) | ((r & 2) << 2) | (r & 4) | ((r & 8) >> 2) | ((r & 16) >> 4);
}

// in-register 32-point DIF FFT; output slot r holds bin br5(r)
__device__ __forceinline__ void fft32(float* vr, float* vi)
{
    constexpr float TR[16] = {
        1.0f, 0.9807852804f, 0.9238795325f, 0.8314696123f,
        0.7071067812f, 0.5555702330f, 0.3826834324f, 0.1950903220f,
        0.0f, -0.1950903220f, -0.3826834324f, -0.5555702330f,
        -0.7071067812f, -0.8314696123f, -0.9238795325f, -0.9807852804f };
    constexpr float TI[16] = {
        0.0f, -0.1950903220f, -0.3826834324f, -0.5555702330f,
        -0.7071067812f, -0.8314696123f, -0.9238795325f, -0.9807852804f,
        -1.0f, -0.9807852804f, -0.9238795325f, -0.8314696123f,
        -0.7071067812f, -0.5555702330f, -0.3826834324f, -0.1950903220f };
    #pragma unroll
    for (int s = 0; s < 5; ++s) {
        const int half = 16 >> s;
        #pragma unroll
        for (int g = 0; g < (1 << s); ++g) {
            #pragma unroll
            for (int jj = 0; jj < half; ++jj) {
                const int i1 = g * (half << 1) + jj;
                const int i2 = i1 + half;
                const int q = jj << s;
                float ar = vr[i1], ai = vi[i1];
                float br = vr[i2], bi = vi[i2];
                vr[i1] = ar + br; vi[i1] = ai + bi;
                float dr = ar - br, di = ai - bi;
                vr[i2] = dr * TR[q] - di * TI[q];
                vi[i2] = dr * TI[q] + di * TR[q];
            }
        }
    }
}

// apply twiddle w^k1 (k1=1..31) to slot br5(k1) via iterative rotation chain
__device__ __forceinline__ void twiddle_chain(float* vr, float* vi, float ang)
{
    float c1, s1;
    __sincosf(ang, &s1, &c1);
    float cw = 1.f, sw = 0.f;
    #pragma unroll
    for (int k1 = 1; k1 < 32; ++k1) {
        float t0 = cw * c1 - sw * s1;
        sw = cw * s1 + sw * c1;
        cw = t0;
        const int r = br5(k1);
        float xr = vr[r], xi = vi[r];
        vr[r] = xr * cw - xi * sw;
        vi[r] = xr * sw + xi * cw;
    }
}

// 8192-pt forward FFT; 64 KB float2 LDS, SINGLE-PASS transposes.
// (Two-pass 32 KB float variant = 12 barriers/kernel, regressed 163->216 us
//  at identical VGPR-bound occupancy — R6 counters. Keep float2.)
// Output: slot r of thread t holds bin k = (t>>3) + 32*br5(r) + 1024*br3(t&7).
__device__ __forceinline__ void big_fft(float* vr, float* vi, float2* lds,
                                        int t, int j, int row)
{
    fft32(vr, vi);
    twiddle_chain(vr, vi, -7.669903939428206e-4f * (float)t);   // -2pi/8192 * t

    __syncthreads();
    #pragma unroll
    for (int r = 0; r < 32; ++r) {
        int a = (br5(r) << 8) + t;
        lds[a ^ (((a >> 8) & 7) << 3)] = make_float2(vr[r], vi[r]);
    }
    __syncthreads();
    #pragma unroll
    for (int m1 = 0; m1 < 32; ++m1) {
        int a = (row << 8) + (m1 << 3) + j;
        float2 v = lds[a ^ (((a >> 8) & 7) << 3)];
        vr[m1] = v.x; vi[m1] = v.y;
    }

    fft32(vr, vi);
    twiddle_chain(vr, vi, -0.02454369260617026f * (float)j);    // -2pi/256 * j

    // cross-lane FFT_8 over j (DIF; output lane j holds bin br3(j))
    const float R2 = 0.7071067811865475f;
    const int jm = j & 3;
    float w1r = 1.f, w1i = 0.f;
    if (j >= 4) {
        w1r = (jm == 0) ? 1.f : (jm == 1) ? R2 : (jm == 2) ? 0.f : -R2;
        w1i = (jm == 0) ? 0.f : (jm == 1) ? -R2 : (jm == 2) ? -1.f : -R2;
    }
    const float sg1 = (j < 4) ? 1.f : -1.f;
    const float sg2 = (j & 2) ? -1.f : 1.f;
    const bool tw2 = (j & 2) && (j & 1);
    const float w2r = tw2 ? 0.f : 1.f;
    const float w2i = tw2 ? -1.f : 0.f;
    const float sg3 = (j & 1) ? -1.f : 1.f;
    #pragma unroll
    for (int r = 0; r < 32; ++r) {
        float orr = __shfl_xor(vr[r], 4);
        float oii = __shfl_xor(vi[r], 4);
        float sr = fmaf(sg1, vr[r], orr);
        float si = fmaf(sg1, vi[r], oii);
        float tr = sr * w1r - si * w1i;
        float ti = sr * w1i + si * w1r;
        orr = __shfl_xor(tr, 2);
        oii = __shfl_xor(ti, 2);
        sr = fmaf(sg2, tr, orr);
        si = fmaf(sg2, ti, oii);
        tr = sr * w2r - si * w2i;
        ti = sr * w2i + si * w2r;
        orr = __shfl_xor(tr, 1);
        oii = __shfl_xor(ti, 1);
        vr[r] = fmaf(sg3, tr, orr);
        vi[r] = fmaf(sg3, ti, oii);
    }
}

// ---------------------------------------------------------------------------
// Kernel 1: Hilbert via register FFT; f16-plane output.
// __launch_bounds__(256) with NO second arg: min-waves w makes the compiler
// budget VGPRs as 256/w — (256,2) capped at 128 and (256,3) at 84, spilling
// vr/vi to scratch (+260..500 MB HBM, R4/R5). Unbounded -> 204 VGPR, no
// spill. Do not add a 2nd arg.
// ---------------------------------------------------------------------------
__global__ __launch_bounds__(256) void fft_hilbert_kernel(
    const float* __restrict__ x, _Float16* __restrict__ zr,
    _Float16* __restrict__ zi)
{
    __shared__ float2 lds[8192];   // 64 KB
    const int sig = blockIdx.x;
    const int t = threadIdx.x;
    const int j = t & 7, row = t >> 3;
    const int br3j = ((j & 1) << 2) | (j & 2) | ((j & 4) >> 2);

    float vr[32], vi[32];
    const float* xp = x + (size_t)sig * T_LEN;
    #pragma unroll
    for (int n1 = 0; n1 < 32; ++n1) { vr[n1] = xp[(n1 << 8) + t]; vi[n1] = 0.f; }

    big_fft(vr, vi, lds, t, j, row);

    // conj + Hilbert filter
    #pragma unroll
    for (int r = 0; r < 32; ++r) {
        const int k = row + (br5(r) << 5) + (br3j << 10);
        const float h = (k == 0 || k == 4096) ? 1.f : (k < 4096 ? 2.f : 0.f);
        vr[r] = vr[r] * h;
        vi[r] = -vi[r] * h;
    }

    // redistribute to natural order (single float2 pass)
    __syncthreads();
    #pragma unroll
    for (int r = 0; r < 32; ++r) {
        int a = row + (br5(r) << 5) + (br3j << 10);
        lds[a ^ (((a >> 10) & 7) << 3)] = make_float2(vr[r], vi[r]);
    }
    __syncthreads();
    #pragma unroll
    for (int n1 = 0; n1 < 32; ++n1) {
        int a = (n1 << 8) + t;
        float2 v = lds[a ^ (((a >> 10) & 7) << 3)];
        vr[n1] = v.x; vi[n1] = v.y;
    }

    big_fft(vr, vi, lds, t, j, row);

    // conj + normalize; store f16 planes (fixed t-permutation, PLV-invariant)
    _Float16* zrp = zr + (size_t)sig * T_LEN;
    _Float16* zip = zi + (size_t)sig * T_LEN;
    #pragma unroll
    for (int r = 0; r < 32; ++r) {
        float ar = vr[r], ai = -vi[r];
        float inv = rsqrtf(ar * ar + ai * ai);
        zrp[(r << 8) + t] = (_Float16)(ar * inv);
        zip[(r << 8) + t] = (_Float16)(ai * inv);
    }
}

// ---------------------------------------------------------------------------
// Kernel 2: Gram via f16 MFMA, software-pipelined staging (unchanged R6).
// ---------------------------------------------------------------------------
#define GS 72   // LDS row stride in f16 (64 + 8 pad)
__global__ __launch_bounds__(256) void gram_kernel(
    const _Float16* __restrict__ zr, const _Float16* __restrict__ zi,
    float* __restrict__ part)
{
    __shared__ _Float16 ReS[64 * GS];
    __shared__ _Float16 ImS[64 * GS];
    const int b = blockIdx.x, sl = blockIdx.y, tid = threadIdx.x;
    const int w = tid >> 6, lane = tid & 63;
    const int mrow = lane & 15, quad = lane >> 4;

    f32x4 acc_re[4], acc_i1[4], acc_i2[4];
    #pragma unroll
    for (int tn = 0; tn < 4; ++tn) {
        acc_re[tn] = (f32x4)0.f; acc_i1[tn] = (f32x4)0.f; acc_i2[tn] = (f32x4)0.f;
    }

    const int k0 = sl * (T_LEN / NS_G);
    const int r0 = tid >> 3, r1 = r0 + 32;
    const int c8 = (tid & 7) * 8;
    const size_t gb = (size_t)b * 64 * T_LEN + k0;

    uint4 pr0 = *(const uint4*)&zr[gb + (size_t)r0 * T_LEN + c8];
    uint4 pi0 = *(const uint4*)&zi[gb + (size_t)r0 * T_LEN + c8];
    uint4 pr1 = *(const uint4*)&zr[gb + (size_t)r1 * T_LEN + c8];
    uint4 pi1 = *(const uint4*)&zi[gb + (size_t)r1 * T_LEN + c8];

    const int NCH = (T_LEN / NS_G) / 64;
    for (int chunk = 0; chunk < NCH; ++chunk) {
        __syncthreads();
        *(uint4*)&ReS[r0 * GS + c8] = pr0;
        *(uint4*)&ImS[r0 * GS + c8] = pi0;
        *(uint4*)&ReS[r1 * GS + c8] = pr1;
        *(uint4*)&ImS[r1 * GS + c8] = pi1;
        __syncthreads();
        if (chunk + 1 < NCH) {
            const size_t gn = gb + (chunk + 1) * 64;
            pr0 = *(const uint4*)&zr[gn + (size_t)r0 * T_LEN + c8];
            pi0 = *(const uint4*)&zi[gn + (size_t)r0 * T_LEN + c8];
            pr1 = *(const uint4*)&zr[gn + (size_t)r1 * T_LEN + c8];
            pi1 = *(const uint4*)&zi[gn + (size_t)r1 * T_LEN + c8];
        }
        #pragma unroll
        for (int ks = 0; ks < 2; ++ks) {
            const int koff = ks * 32 + quad * 8;
            f16x8 a_re = *(f16x8*)&ReS[(w * 16 + mrow) * GS + koff];
            f16x8 a_im = *(f16x8*)&ImS[(w * 16 + mrow) * GS + koff];
            #pragma unroll
            for (int tn = 0; tn < 4; ++tn) {
                f16x8 b_re = *(f16x8*)&ReS[(tn * 16 + mrow) * GS + koff];
                f16x8 b_im = *(f16x8*)&ImS[(tn * 16 + mrow) * GS + koff];
                acc_re[tn] = __builtin_amdgcn_mfma_f32_16x16x32_f16(a_re, b_re, acc_re[tn], 0, 0, 0);
                acc_re[tn] = __builtin_amdgcn_mfma_f32_16x16x32_f16(a_im, b_im, acc_re[tn], 0, 0, 0);
                acc_i1[tn] = __builtin_amdgcn_mfma_f32_16x16x32_f16(a_im, b_re, acc_i1[tn], 0, 0, 0);
                acc_i2[tn] = __builtin_amdgcn_mfma_f32_16x16x32_f16(a_re, b_im, acc_i2[tn], 0, 0, 0);
            }
        }
    }

    float2* pp = (float2*)part + (size_t)(b * NS_G + sl) * 4096;
    #pragma unroll
    for (int tn = 0; tn < 4; ++tn)
        #pragma unroll
        for (int reg = 0; reg < 4; ++reg) {
            int m = w * 16 + quad * 4 + reg;
            int n = tn * 16 + mrow;
            float2 v;
            v.x = acc_re[tn][reg];
            v.y = acc_i1[tn][reg] - acc_i2[tn][reg];
            pp[m * 64 + n] = v;
        }
}

// ---------------------------------------------------------------------------
// Kernel 3: PLV-reduce + GCN + MHA (unchanged)
// ---------------------------------------------------------------------------
__global__ __launch_bounds__(1024) void gnn_mha_kernel(
    const float* __restrict__ part, const float* __restrict__ emb,
    const float* __restrict__ w1,   const float* __restrict__ b1,
    const float* __restrict__ w2,   const float* __restrict__ b2,
    const float* __restrict__ ipw,  const float* __restrict__ ipb,
    const float* __restrict__ opw,  const float* __restrict__ opb,
    float* __restrict__ out0, float* __restrict__ out1,
    float* __restrict__ out2)
{
    __shared__ float S[16384];
    const int b = blockIdx.x, tid = threadIdx.x;
    const int lane = tid & 63, w = tid >> 6;
    const int i0 = w * 4;

    const float2* pf = (const float2*)part;
    for (int e = tid; e < 4096; e += 1024) {
        float gr = 0.f, gi = 0.f;
        #pragma unroll
        for (int s = 0; s < NS_G; ++s) {
            float2 v = pf[(size_t)(b * NS_G + s) * 4096 + e];
            gr += v.x; gi += v.y;
        }
        int i = e >> 6, jj = e & 63;
        float val = (i == jj) ? 0.f
                              : sqrtf(gr * gr + gi * gi) * (1.0f / 8192.0f);
        S[e] = val;
        out0[(size_t)b * 4096 + e] = val;
    }
    __syncthreads();

    {   // M = conn @ emb
        float acc[4] = {0.f, 0.f, 0.f, 0.f};
        #pragma unroll 8
        for (int k = 0; k < 64; ++k) {
            float ev = emb[k * 64 + lane];
            #pragma unroll
            for (int r = 0; r < 4; ++r)
                acc[r] = fmaf(S[(i0 + r) * 64 + k], ev, acc[r]);
        }
        #pragma unroll
        for (int r = 0; r < 4; ++r) S[4096 + (i0 + r) * 64 + lane] = acc[r];
    }
    __syncthreads();

    {   // h1 = relu(M @ w1 + b1)
        float a0[4] = {0.f, 0.f, 0.f, 0.f}, a1[4] = {0.f, 0.f, 0.f, 0.f};
        #pragma unroll 8
        for (int k = 0; k < 64; ++k) {
            float wa = w1[k * 128 + lane];
            float wb = w1[k * 128 + 64 + lane];
            #pragma unroll
            for (int r = 0; r < 4; ++r) {
                float m = S[4096 + (i0 + r) * 64 + k];
                a0[r] = fmaf(m, wa, a0[r]);
                a1[r] = fmaf(m, wb, a1[r]);
            }
        }
        float bb0 = b1[lane], bb1 = b1[64 + lane];
        #pragma unroll
        for (int r = 0; r < 4; ++r) {
            S[8192 + (i0 + r) * 128 + lane]      = fmaxf(a0[r] + bb0, 0.f);
            S[8192 + (i0 + r) * 128 + 64 + lane] = fmaxf(a1[r] + bb1, 0.f);
        }
    }
    __syncthreads();

    {   // P = h1 @ w2
        float acc[4] = {0.f, 0.f, 0.f, 0.f};
        #pragma unroll 8
        for (int c = 0; c < 128; ++c) {
            float wv = w2[c * 64 + lane];
            #pragma unroll
            for (int r = 0; r < 4; ++r)
                acc[r] = fmaf(S[8192 + (i0 + r) * 128 + c], wv, acc[r]);
        }
        __syncthreads();
        #pragma unroll
        for (int r = 0; r < 4; ++r) S[4096 + (i0 + r) * 64 + lane] = acc[r];
    }
    __syncthreads();

    {   // h2 = conn @ P + b2 (in-place over conn rows)
        float acc[4] = {0.f, 0.f, 0.f, 0.f};
        #pragma unroll 8
        for (int k = 0; k < 64; ++k) {
            float pv = S[4096 + k * 64 + lane];
            #pragma unroll
            for (int r = 0; r < 4; ++r)
                acc[r] = fmaf(S[(i0 + r) * 64 + k], pv, acc[r]);
        }
        float bb = b2[lane];
        #pragma unroll
        for (int r = 0; r < 4; ++r) {
            float v = acc[r] + bb;
            S[(i0 + r) * 64 + lane] = v;
            out2[(size_t)b * 4096 + (i0 + r) * 64 + lane] = v;
        }
    }
    __syncthreads();

    {   // qkv
        float aq[4] = {0.f, 0.f, 0.f, 0.f};
        float ak[4] = {0.f, 0.f, 0.f, 0.f};
        float av[4] = {0.f, 0.f, 0.f, 0.f};
        #pragma unroll 8
        for (int k = 0; k < 64; ++k) {
            float wq = ipw[lane * 64 + k];
            float wk = ipw[(64 + lane) * 64 + k];
            float wv = ipw[(128 + lane) * 64 + k];
            #pragma unroll
            for (int r = 0; r < 4; ++r) {
                float hv = S[(i0 + r) * 64 + k];
                aq[r] = fmaf(hv, wq, aq[r]);
                ak[r] = fmaf(hv, wk, ak[r]);
                av[r] = fmaf(hv, wv, av[r]);
            }
        }
        float bq = ipb[lane], bk = ipb[64 + lane], bv = ipb[128 + lane];
        __syncthreads();
        #pragma unroll
        for (int r = 0; r < 4; ++r) {
            S[4096  + (i0 + r) * 64 + lane] = aq[r] + bq;
            S[8192  + (i0 + r) * 64 + lane] = ak[r] + bk;
            S[12288 + (i0 + r) * 64 + lane] = av[r] + bv;
        }
    }
    __syncthreads();

    const int h = w >> 1;
    float kk[8];
    #pragma unroll
    for (int d = 0; d < 8; ++d) kk[d] = S[8192 + lane * 64 + h * 8 + d];
    __syncthreads();

    {   // scores + softmax + attn@V
        const float iscale = 0.35355339059327373f;
        const int mc = lane >> 3, dd = lane & 7;
        for (int rr = 0; rr < 32; ++rr) {
            const int n = (w & 1) * 32 + rr;
            float s = 0.f;
            #pragma unroll
            for (int d = 0; d < 8; ++d)
                s = fmaf(S[4096 + n * 64 + h * 8 + d], kk[d], s);
            s *= iscale;
            float mx = s;
            #pragma unroll
            for (int off = 1; off < 64; off <<= 1)
                mx = fmaxf(mx, __shfl_xor(mx, off));
            float ev = __expf(s - mx);
            float sum = ev;
            #pragma unroll
            for (int off = 1; off < 64; off <<= 1)
                sum += __shfl_xor(sum, off);
            S[8192 + w * 68 + lane] = ev / sum;
            float o = 0.f;
            #pragma unroll
            for (int jx = 0; jx < 8; ++jx)
                o = fmaf(S[8192 + w * 68 + mc * 8 + jx],
                         S[12288 + (mc * 8 + jx) * 64 + h * 8 + dd], o);
            o += __shfl_xor(o, 8);
            o += __shfl_xor(o, 16);
            o += __shfl_xor(o, 32);
            if (lane < 8) S[n * 64 + h * 8 + lane] = o;
        }
    }
    __syncthreads();

    for (int e = tid; e < 4096; e += 1024) {
        int r = e >> 6, c = e & 63;
        S[8192 + r * 65 + c] = opw[e];
    }
    __syncthreads();

    {   // out1 = oh @ opw^T + opb
        float acc[4] = {0.f, 0.f, 0.f, 0.f};
        #pragma unroll 8
        for (int c = 0; c < 64; ++c) {
            float wv = S[8192 + lane * 65 + c];
            #pragma unroll
            for (int r = 0; r < 4; ++r)
                acc[r] = fmaf(S[(i0 + r) * 64 + c], wv, acc[r]);
        }
        float ob = opb[lane];
        #pragma unroll
        for (int r = 0; r < 4; ++r)
            out1[(size_t)b * 4096 + (i0 + r) * 64 + lane] = acc[r] + ob;
    }
}

// ---------------------------------------------------------------------------
extern "C" void kernel_launch(void* const* d_in, const int* in_sizes, int n_in,
                              void* d_out, int out_size, void* d_ws, size_t ws_size,
                              hipStream_t stream)
{
    const float* x   = (const float*)d_in[0];
    const float* emb = (const float*)d_in[1];
    const float* w1  = (const float*)d_in[2];
    const float* b1  = (const float*)d_in[3];
    const float* w2  = (const float*)d_in[4];
    const float* b2  = (const float*)d_in[5];
    const float* ipw = (const float*)d_in[6];
    const float* ipb = (const float*)d_in[7];
    const float* opw = (const float*)d_in[8];
    const float* opb = (const float*)d_in[9];

    float* out  = (float*)d_out;
    float* out0 = out;
    float* out1 = out + 131072;
    float* out2 = out + 262144;

    _Float16* zr = (_Float16*)d_ws;                     // 32 MB
    _Float16* zi = zr + (size_t)2048 * T_LEN;           // 32 MB
    float* part  = (float*)(zi + (size_t)2048 * T_LEN); // 8 MB

    hipLaunchKernelGGL(fft_hilbert_kernel, dim3(32 * 64), dim3(256), 0, stream,
                       x, zr, zi);
    hipLaunchKernelGGL(gram_kernel, dim3(32, NS_G), dim3(256), 0, stream,
                       zr, zi, part);
    hipLaunchKernelGGL(gnn_mha_kernel, dim3(32), dim3(1024), 0, stream,
                       part, emb, w1, b1, w2, b2, ipw, ipb, opw, opb,
                       out0, out1, out2);
}

// Round 8
// 335.100 us; speedup vs baseline: 1.0062x; 1.0062x over previous
//
#include <hip/hip_runtime.h>
#include <math.h>

#define T_LEN 8192
#define NS_G 8   // gram K-slices

typedef float  f32x4 __attribute__((ext_vector_type(4)));
typedef _Float16 f16x8 __attribute__((ext_vector_type(8)));

__device__ __forceinline__ constexpr int br5(int r) {
    return ((r & 1) << 4) | ((r & 2) << 2) | (r & 4) | ((r & 8) >> 2) | ((r & 16) >> 4);
}

// in-register 32-point DIF FFT; output slot r holds bin br5(r)
__device__ __forceinline__ void fft32(float* vr, float* vi)
{
    constexpr float TR[16] = {
        1.0f, 0.9807852804f, 0.9238795325f, 0.8314696123f,
        0.7071067812f, 0.5555702330f, 0.3826834324f, 0.1950903220f,
        0.0f, -0.1950903220f, -0.3826834324f, -0.5555702330f,
        -0.7071067812f, -0.8314696123f, -0.9238795325f, -0.9807852804f };
    constexpr float TI[16] = {
        0.0f, -0.1950903220f, -0.3826834324f, -0.5555702330f,
        -0.7071067812f, -0.8314696123f, -0.9238795325f, -0.9807852804f,
        -1.0f, -0.9807852804f, -0.9238795325f, -0.8314696123f,
        -0.7071067812f, -0.5555702330f, -0.3826834324f, -0.1950903220f };
    #pragma unroll
    for (int s = 0; s < 5; ++s) {
        const int half = 16 >> s;
        #pragma unroll
        for (int g = 0; g < (1 << s); ++g) {
            #pragma unroll
            for (int jj = 0; jj < half; ++jj) {
                const int i1 = g * (half << 1) + jj;
                const int i2 = i1 + half;
                const int q = jj << s;
                float ar = vr[i1], ai = vi[i1];
                float br = vr[i2], bi = vi[i2];
                vr[i1] = ar + br; vi[i1] = ai + bi;
                float dr = ar - br, di = ai - bi;
                vr[i2] = dr * TR[q] - di * TI[q];
                vi[i2] = dr * TI[q] + di * TR[q];
            }
        }
    }
}

// 8192-pt forward FFT; 64 KB float2 LDS, single-pass transposes, and
// INDEPENDENT per-slot sincos twiddles.
// NOTE (R6/R7 post-mortem): the "cheaper" iterative rotation chain is a
// 31-step serial dependency — at 2 waves/SIMD it is latency-bound and
// regressed 163->216/227 us (VALUBusy 42->30%). 31 independent __sincosf
// issue with full ILP and win. Do not reintroduce the chain.
// Output: slot r of thread t holds bin k = (t>>3) + 32*br5(r) + 1024*br3(t&7).
__device__ __forceinline__ void big_fft(float* vr, float* vi, float2* lds,
                                        int t, int j, int row)
{
    fft32(vr, vi);
    const float base1 = -7.669903939428206e-4f * (float)t;   // -2pi/8192 * t
    #pragma unroll
    for (int r = 0; r < 32; ++r) {
        const int k1 = br5(r);
        if (k1) {
            float c, s; __sincosf(base1 * (float)k1, &s, &c);
            float xr = vr[r], xi = vi[r];
            vr[r] = xr * c - xi * s;
            vi[r] = xr * s + xi * c;
        }
    }
    __syncthreads();
    #pragma unroll
    for (int r = 0; r < 32; ++r) {
        int a = (br5(r) << 8) + t;
        lds[a ^ (((a >> 8) & 7) << 3)] = make_float2(vr[r], vi[r]);
    }
    __syncthreads();
    #pragma unroll
    for (int m1 = 0; m1 < 32; ++m1) {
        int a = (row << 8) + (m1 << 3) + j;
        float2 v = lds[a ^ (((a >> 8) & 7) << 3)];
        vr[m1] = v.x; vi[m1] = v.y;
    }

    fft32(vr, vi);
    const float base2 = -0.02454369260617026f * (float)j;     // -2pi/256 * j
    #pragma unroll
    for (int r = 0; r < 32; ++r) {
        const int k1p = br5(r);
        if (k1p) {
            float c, s; __sincosf(base2 * (float)k1p, &s, &c);
            float xr = vr[r], xi = vi[r];
            vr[r] = xr * c - xi * s;
            vi[r] = xr * s + xi * c;
        }
    }
    // cross-lane FFT_8 over j (DIF; output lane j holds bin br3(j))
    const float R2 = 0.7071067811865475f;
    const int jm = j & 3;
    float w1r = 1.f, w1i = 0.f;
    if (j >= 4) {
        w1r = (jm == 0) ? 1.f : (jm == 1) ? R2 : (jm == 2) ? 0.f : -R2;
        w1i = (jm == 0) ? 0.f : (jm == 1) ? -R2 : (jm == 2) ? -1.f : -R2;
    }
    const float sg1 = (j < 4) ? 1.f : -1.f;
    const float sg2 = (j & 2) ? -1.f : 1.f;
    const bool tw2 = (j & 2) && (j & 1);
    const float w2r = tw2 ? 0.f : 1.f;
    const float w2i = tw2 ? -1.f : 0.f;
    const float sg3 = (j & 1) ? -1.f : 1.f;
    #pragma unroll
    for (int r = 0; r < 32; ++r) {
        float orr = __shfl_xor(vr[r], 4);
        float oii = __shfl_xor(vi[r], 4);
        float sr = fmaf(sg1, vr[r], orr);
        float si = fmaf(sg1, vi[r], oii);
        float tr = sr * w1r - si * w1i;
        float ti = sr * w1i + si * w1r;
        orr = __shfl_xor(tr, 2);
        oii = __shfl_xor(ti, 2);
        sr = fmaf(sg2, tr, orr);
        si = fmaf(sg2, ti, oii);
        tr = sr * w2r - si * w2i;
        ti = sr * w2i + si * w2r;
        orr = __shfl_xor(tr, 1);
        oii = __shfl_xor(ti, 1);
        vr[r] = fmaf(sg3, tr, orr);
        vi[r] = fmaf(sg3, ti, oii);
    }
}

// ---------------------------------------------------------------------------
// Kernel 1: Hilbert via register FFT; f16-plane output.
// __launch_bounds__(256) with NO second arg: min-waves w makes the compiler
// budget VGPRs as 256/w — (256,2) capped at 128 and (256,3) at 84, spilling
// vr/vi to scratch (+260..500 MB HBM, R4/R5). Unbounded -> ~204 VGPR, no
// spill. Do not add a 2nd arg.
// ---------------------------------------------------------------------------
__global__ __launch_bounds__(256) void fft_hilbert_kernel(
    const float* __restrict__ x, _Float16* __restrict__ zr,
    _Float16* __restrict__ zi)
{
    __shared__ float2 lds[8192];   // 64 KB
    const int sig = blockIdx.x;
    const int t = threadIdx.x;
    const int j = t & 7, row = t >> 3;
    const int br3j = ((j & 1) << 2) | (j & 2) | ((j & 4) >> 2);

    float vr[32], vi[32];
    const float* xp = x + (size_t)sig * T_LEN;
    #pragma unroll
    for (int n1 = 0; n1 < 32; ++n1) { vr[n1] = xp[(n1 << 8) + t]; vi[n1] = 0.f; }

    big_fft(vr, vi, lds, t, j, row);

    // conj + Hilbert filter
    #pragma unroll
    for (int r = 0; r < 32; ++r) {
        const int k = row + (br5(r) << 5) + (br3j << 10);
        const float h = (k == 0 || k == 4096) ? 1.f : (k < 4096 ? 2.f : 0.f);
        vr[r] = vr[r] * h;
        vi[r] = -vi[r] * h;
    }

    // redistribute to natural order (single float2 pass)
    __syncthreads();
    #pragma unroll
    for (int r = 0; r < 32; ++r) {
        int a = row + (br5(r) << 5) + (br3j << 10);
        lds[a ^ (((a >> 10) & 7) << 3)] = make_float2(vr[r], vi[r]);
    }
    __syncthreads();
    #pragma unroll
    for (int n1 = 0; n1 < 32; ++n1) {
        int a = (n1 << 8) + t;
        float2 v = lds[a ^ (((a >> 10) & 7) << 3)];
        vr[n1] = v.x; vi[n1] = v.y;
    }

    big_fft(vr, vi, lds, t, j, row);

    // conj + normalize; store f16 planes (fixed t-permutation, PLV-invariant)
    _Float16* zrp = zr + (size_t)sig * T_LEN;
    _Float16* zip = zi + (size_t)sig * T_LEN;
    #pragma unroll
    for (int r = 0; r < 32; ++r) {
        float ar = vr[r], ai = -vi[r];
        float inv = rsqrtf(ar * ar + ai * ai);
        zrp[(r << 8) + t] = (_Float16)(ar * inv);
        zip[(r << 8) + t] = (_Float16)(ai * inv);
    }
}

// ---------------------------------------------------------------------------
// Kernel 2: Gram via f16 MFMA, software-pipelined staging (unchanged).
// ---------------------------------------------------------------------------
#define GS 72   // LDS row stride in f16 (64 + 8 pad)
__global__ __launch_bounds__(256) void gram_kernel(
    const _Float16* __restrict__ zr, const _Float16* __restrict__ zi,
    float* __restrict__ part)
{
    __shared__ _Float16 ReS[64 * GS];
    __shared__ _Float16 ImS[64 * GS];
    const int b = blockIdx.x, sl = blockIdx.y, tid = threadIdx.x;
    const int w = tid >> 6, lane = tid & 63;
    const int mrow = lane & 15, quad = lane >> 4;

    f32x4 acc_re[4], acc_i1[4], acc_i2[4];
    #pragma unroll
    for (int tn = 0; tn < 4; ++tn) {
        acc_re[tn] = (f32x4)0.f; acc_i1[tn] = (f32x4)0.f; acc_i2[tn] = (f32x4)0.f;
    }

    const int k0 = sl * (T_LEN / NS_G);
    const int r0 = tid >> 3, r1 = r0 + 32;
    const int c8 = (tid & 7) * 8;
    const size_t gb = (size_t)b * 64 * T_LEN + k0;

    uint4 pr0 = *(const uint4*)&zr[gb + (size_t)r0 * T_LEN + c8];
    uint4 pi0 = *(const uint4*)&zi[gb + (size_t)r0 * T_LEN + c8];
    uint4 pr1 = *(const uint4*)&zr[gb + (size_t)r1 * T_LEN + c8];
    uint4 pi1 = *(const uint4*)&zi[gb + (size_t)r1 * T_LEN + c8];

    const int NCH = (T_LEN / NS_G) / 64;
    for (int chunk = 0; chunk < NCH; ++chunk) {
        __syncthreads();
        *(uint4*)&ReS[r0 * GS + c8] = pr0;
        *(uint4*)&ImS[r0 * GS + c8] = pi0;
        *(uint4*)&ReS[r1 * GS + c8] = pr1;
        *(uint4*)&ImS[r1 * GS + c8] = pi1;
        __syncthreads();
        if (chunk + 1 < NCH) {
            const size_t gn = gb + (chunk + 1) * 64;
            pr0 = *(const uint4*)&zr[gn + (size_t)r0 * T_LEN + c8];
            pi0 = *(const uint4*)&zi[gn + (size_t)r0 * T_LEN + c8];
            pr1 = *(const uint4*)&zr[gn + (size_t)r1 * T_LEN + c8];
            pi1 = *(const uint4*)&zi[gn + (size_t)r1 * T_LEN + c8];
        }
        #pragma unroll
        for (int ks = 0; ks < 2; ++ks) {
            const int koff = ks * 32 + quad * 8;
            f16x8 a_re = *(f16x8*)&ReS[(w * 16 + mrow) * GS + koff];
            f16x8 a_im = *(f16x8*)&ImS[(w * 16 + mrow) * GS + koff];
            #pragma unroll
            for (int tn = 0; tn < 4; ++tn) {
                f16x8 b_re = *(f16x8*)&ReS[(tn * 16 + mrow) * GS + koff];
                f16x8 b_im = *(f16x8*)&ImS[(tn * 16 + mrow) * GS + koff];
                acc_re[tn] = __builtin_amdgcn_mfma_f32_16x16x32_f16(a_re, b_re, acc_re[tn], 0, 0, 0);
                acc_re[tn] = __builtin_amdgcn_mfma_f32_16x16x32_f16(a_im, b_im, acc_re[tn], 0, 0, 0);
                acc_i1[tn] = __builtin_amdgcn_mfma_f32_16x16x32_f16(a_im, b_re, acc_i1[tn], 0, 0, 0);
                acc_i2[tn] = __builtin_amdgcn_mfma_f32_16x16x32_f16(a_re, b_im, acc_i2[tn], 0, 0, 0);
            }
        }
    }

    float2* pp = (float2*)part + (size_t)(b * NS_G + sl) * 4096;
    #pragma unroll
    for (int tn = 0; tn < 4; ++tn)
        #pragma unroll
        for (int reg = 0; reg < 4; ++reg) {
            int m = w * 16 + quad * 4 + reg;
            int n = tn * 16 + mrow;
            float2 v;
            v.x = acc_re[tn][reg];
            v.y = acc_i1[tn][reg] - acc_i2[tn][reg];
            pp[m * 64 + n] = v;
        }
}

// ---------------------------------------------------------------------------
// Kernel 3: PLV-reduce + GCN + MHA (unchanged)
// ---------------------------------------------------------------------------
__global__ __launch_bounds__(1024) void gnn_mha_kernel(
    const float* __restrict__ part, const float* __restrict__ emb,
    const float* __restrict__ w1,   const float* __restrict__ b1,
    const float* __restrict__ w2,   const float* __restrict__ b2,
    const float* __restrict__ ipw,  const float* __restrict__ ipb,
    const float* __restrict__ opw,  const float* __restrict__ opb,
    float* __restrict__ out0, float* __restrict__ out1,
    float* __restrict__ out2)
{
    __shared__ float S[16384];
    const int b = blockIdx.x, tid = threadIdx.x;
    const int lane = tid & 63, w = tid >> 6;
    const int i0 = w * 4;

    const float2* pf = (const float2*)part;
    for (int e = tid; e < 4096; e += 1024) {
        float gr = 0.f, gi = 0.f;
        #pragma unroll
        for (int s = 0; s < NS_G; ++s) {
            float2 v = pf[(size_t)(b * NS_G + s) * 4096 + e];
            gr += v.x; gi += v.y;
        }
        int i = e >> 6, jj = e & 63;
        float val = (i == jj) ? 0.f
                              : sqrtf(gr * gr + gi * gi) * (1.0f / 8192.0f);
        S[e] = val;
        out0[(size_t)b * 4096 + e] = val;
    }
    __syncthreads();

    {   // M = conn @ emb
        float acc[4] = {0.f, 0.f, 0.f, 0.f};
        #pragma unroll 8
        for (int k = 0; k < 64; ++k) {
            float ev = emb[k * 64 + lane];
            #pragma unroll
            for (int r = 0; r < 4; ++r)
                acc[r] = fmaf(S[(i0 + r) * 64 + k], ev, acc[r]);
        }
        #pragma unroll
        for (int r = 0; r < 4; ++r) S[4096 + (i0 + r) * 64 + lane] = acc[r];
    }
    __syncthreads();

    {   // h1 = relu(M @ w1 + b1)
        float a0[4] = {0.f, 0.f, 0.f, 0.f}, a1[4] = {0.f, 0.f, 0.f, 0.f};
        #pragma unroll 8
        for (int k = 0; k < 64; ++k) {
            float wa = w1[k * 128 + lane];
            float wb = w1[k * 128 + 64 + lane];
            #pragma unroll
            for (int r = 0; r < 4; ++r) {
                float m = S[4096 + (i0 + r) * 64 + k];
                a0[r] = fmaf(m, wa, a0[r]);
                a1[r] = fmaf(m, wb, a1[r]);
            }
        }
        float bb0 = b1[lane], bb1 = b1[64 + lane];
        #pragma unroll
        for (int r = 0; r < 4; ++r) {
            S[8192 + (i0 + r) * 128 + lane]      = fmaxf(a0[r] + bb0, 0.f);
            S[8192 + (i0 + r) * 128 + 64 + lane] = fmaxf(a1[r] + bb1, 0.f);
        }
    }
    __syncthreads();

    {   // P = h1 @ w2
        float acc[4] = {0.f, 0.f, 0.f, 0.f};
        #pragma unroll 8
        for (int c = 0; c < 128; ++c) {
            float wv = w2[c * 64 + lane];
            #pragma unroll
            for (int r = 0; r < 4; ++r)
                acc[r] = fmaf(S[8192 + (i0 + r) * 128 + c], wv, acc[r]);
        }
        __syncthreads();
        #pragma unroll
        for (int r = 0; r < 4; ++r) S[4096 + (i0 + r) * 64 + lane] = acc[r];
    }
    __syncthreads();

    {   // h2 = conn @ P + b2 (in-place over conn rows)
        float acc[4] = {0.f, 0.f, 0.f, 0.f};
        #pragma unroll 8
        for (int k = 0; k < 64; ++k) {
            float pv = S[4096 + k * 64 + lane];
            #pragma unroll
            for (int r = 0; r < 4; ++r)
                acc[r] = fmaf(S[(i0 + r) * 64 + k], pv, acc[r]);
        }
        float bb = b2[lane];
        #pragma unroll
        for (int r = 0; r < 4; ++r) {
            float v = acc[r] + bb;
            S[(i0 + r) * 64 + lane] = v;
            out2[(size_t)b * 4096 + (i0 + r) * 64 + lane] = v;
        }
    }
    __syncthreads();

    {   // qkv
        float aq[4] = {0.f, 0.f, 0.f, 0.f};
        float ak[4] = {0.f, 0.f, 0.f, 0.f};
        float av[4] = {0.f, 0.f, 0.f, 0.f};
        #pragma unroll 8
        for (int k = 0; k < 64; ++k) {
            float wq = ipw[lane * 64 + k];
            float wk = ipw[(64 + lane) * 64 + k];
            float wv = ipw[(128 + lane) * 64 + k];
            #pragma unroll
            for (int r = 0; r < 4; ++r) {
                float hv = S[(i0 + r) * 64 + k];
                aq[r] = fmaf(hv, wq, aq[r]);
                ak[r] = fmaf(hv, wk, ak[r]);
                av[r] = fmaf(hv, wv, av[r]);
            }
        }
        float bq = ipb[lane], bk = ipb[64 + lane], bv = ipb[128 + lane];
        __syncthreads();
        #pragma unroll
        for (int r = 0; r < 4; ++r) {
            S[4096  + (i0 + r) * 64 + lane] = aq[r] + bq;
            S[8192  + (i0 + r) * 64 + lane] = ak[r] + bk;
            S[12288 + (i0 + r) * 64 + lane] = av[r] + bv;
        }
    }
    __syncthreads();

    const int h = w >> 1;
    float kk[8];
    #pragma unroll
    for (int d = 0; d < 8; ++d) kk[d] = S[8192 + lane * 64 + h * 8 + d];
    __syncthreads();

    {   // scores + softmax + attn@V
        const float iscale = 0.35355339059327373f;
        const int mc = lane >> 3, dd = lane & 7;
        for (int rr = 0; rr < 32; ++rr) {
            const int n = (w & 1) * 32 + rr;
            float s = 0.f;
            #pragma unroll
            for (int d = 0; d < 8; ++d)
                s = fmaf(S[4096 + n * 64 + h * 8 + d], kk[d], s);
            s *= iscale;
            float mx = s;
            #pragma unroll
            for (int off = 1; off < 64; off <<= 1)
                mx = fmaxf(mx, __shfl_xor(mx, off));
            float ev = __expf(s - mx);
            float sum = ev;
            #pragma unroll
            for (int off = 1; off < 64; off <<= 1)
                sum += __shfl_xor(sum, off);
            S[8192 + w * 68 + lane] = ev / sum;
            float o = 0.f;
            #pragma unroll
            for (int jx = 0; jx < 8; ++jx)
                o = fmaf(S[8192 + w * 68 + mc * 8 + jx],
                         S[12288 + (mc * 8 + jx) * 64 + h * 8 + dd], o);
            o += __shfl_xor(o, 8);
            o += __shfl_xor(o, 16);
            o += __shfl_xor(o, 32);
            if (lane < 8) S[n * 64 + h * 8 + lane] = o;
        }
    }
    __syncthreads();

    for (int e = tid; e < 4096; e += 1024) {
        int r = e >> 6, c = e & 63;
        S[8192 + r * 65 + c] = opw[e];
    }
    __syncthreads();

    {   // out1 = oh @ opw^T + opb
        float acc[4] = {0.f, 0.f, 0.f, 0.f};
        #pragma unroll 8
        for (int c = 0; c < 64; ++c) {
            float wv = S[8192 + lane * 65 + c];
            #pragma unroll
            for (int r = 0; r < 4; ++r)
                acc[r] = fmaf(S[(i0 + r) * 64 + c], wv, acc[r]);
        }
        float ob = opb[lane];
        #pragma unroll
        for (int r = 0; r < 4; ++r)
            out1[(size_t)b * 4096 + (i0 + r) * 64 + lane] = acc[r] + ob;
    }
}

// ---------------------------------------------------------------------------
extern "C" void kernel_launch(void* const* d_in, const int* in_sizes, int n_in,
                              void* d_out, int out_size, void* d_ws, size_t ws_size,
                              hipStream_t stream)
{
    const float* x   = (const float*)d_in[0];
    const float* emb = (const float*)d_in[1];
    const float* w1  = (const float*)d_in[2];
    const float* b1  = (const float*)d_in[3];
    const float* w2  = (const float*)d_in[4];
    const float* b2  = (const float*)d_in[5];
    const float* ipw = (const float*)d_in[6];
    const float* ipb = (const float*)d_in[7];
    const float* opw = (const float*)d_in[8];
    const float* opb = (const float*)d_in[9];

    float* out  = (float*)d_out;
    float* out0 = out;
    float* out1 = out + 131072;
    float* out2 = out + 262144;

    _Float16* zr = (_Float16*)d_ws;                     // 32 MB
    _Float16* zi = zr + (size_t)2048 * T_LEN;           // 32 MB
    float* part  = (float*)(zi + (size_t)2048 * T_LEN); // 8 MB

    hipLaunchKernelGGL(fft_hilbert_kernel, dim3(32 * 64), dim3(256), 0, stream,
                       x, zr, zi);
    hipLaunchKernelGGL(gram_kernel, dim3(32, NS_G), dim3(256), 0, stream,
                       zr, zi, part);
    hipLaunchKernelGGL(gnn_mha_kernel, dim3(32), dim3(1024), 0, stream,
                       part, emb, w1, b1, w2, b2, ipw, ipb, opw, opb,
                       out0, out1, out2);
}

// Round 9
// 330.562 us; speedup vs baseline: 1.0200x; 1.0137x over previous
//
#include <hip/hip_runtime.h>
#include <math.h>

#define T_LEN 8192
#define NS_G 8   // gram K-slices

typedef float  f32x4 __attribute__((ext_vector_type(4)));
typedef _Float16 f16x8 __attribute__((ext_vector_type(8)));
typedef float  cpx   __attribute__((ext_vector_type(2)));   // (re, im) in a VGPR pair

// ---- packed fp32 complex primitives (VOP3P) --------------------------------
// d = a + b  (componentwise)
#define CADD(d, a, b) \
    asm("v_pk_add_f32 %0, %1, %2" : "=v"(d) : "v"(a), "v"(b))
// d = a - b
#define CSUB(d, a, b) \
    asm("v_pk_add_f32 %0, %1, %2 neg_lo:[0,1] neg_hi:[0,1]" : "=v"(d) : "v"(a), "v"(b))
// d = s*a + b  (componentwise fma; s usually a broadcast pair)
#define CFMA(d, s, a, b) \
    asm("v_pk_fma_f32 %0, %1, %2, %3" : "=v"(d) : "v"(s), "v"(a), "v"(b))
// d = x * w, complex multiply, w = (c, s):
//   t  = (xr*c, xi*c)
//   d  = (t.lo - xi*s, t.hi + xr*s)
#define CMUL(d, x, w) do { cpx _t_;                                            \
    asm("v_pk_mul_f32 %0, %1, %2 op_sel:[0,0] op_sel_hi:[1,0]"                 \
        : "=v"(_t_) : "v"(x), "v"(w));                                         \
    asm("v_pk_fma_f32 %0, %1, %2, %3 op_sel:[1,1,0] op_sel_hi:[0,1,1] "        \
        "neg_lo:[1,0,0] neg_hi:[0,0,0]"                                        \
        : "=v"(d) : "v"(x), "v"(w), "v"(_t_)); } while (0)

__device__ __forceinline__ constexpr int br5(int r) {
    return ((r & 1) << 4) | ((r & 2) << 2) | (r & 4) | ((r & 8) >> 2) | ((r & 16) >> 4);
}

// in-register 32-point DIF FFT, packed complex; output slot r holds bin br5(r)
__device__ __forceinline__ void fft32p(cpx* v)
{
    constexpr float TR[16] = {
        1.0f, 0.9807852804f, 0.9238795325f, 0.8314696123f,
        0.7071067812f, 0.5555702330f, 0.3826834324f, 0.1950903220f,
        0.0f, -0.1950903220f, -0.3826834324f, -0.5555702330f,
        -0.7071067812f, -0.8314696123f, -0.9238795325f, -0.9807852804f };
    constexpr float TI[16] = {
        0.0f, -0.1950903220f, -0.3826834324f, -0.5555702330f,
        -0.7071067812f, -0.8314696123f, -0.9238795325f, -0.9807852804f,
        -1.0f, -0.9807852804f, -0.9238795325f, -0.8314696123f,
        -0.7071067812f, -0.5555702330f, -0.3826834324f, -0.1950903220f };
    #pragma unroll
    for (int s = 0; s < 5; ++s) {
        const int half = 16 >> s;
        #pragma unroll
        for (int g = 0; g < (1 << s); ++g) {
            #pragma unroll
            for (int jj = 0; jj < half; ++jj) {
                const int i1 = g * (half << 1) + jj;
                const int i2 = i1 + half;
                const int q = jj << s;
                cpx a = v[i1], b = v[i2], u, d;
                CADD(u, a, b);
                CSUB(d, a, b);
                v[i1] = u;
                if (q == 0) {
                    v[i2] = d;
                } else {
                    cpx w; w.x = TR[q]; w.y = TI[q];
                    cpx o; CMUL(o, d, w);
                    v[i2] = o;
                }
            }
        }
    }
}

// 8192-pt forward FFT; 64 KB cpx LDS, single-pass transposes, independent
// per-slot sincos twiddles (R7 post-mortem: serial rotation chain is
// latency-bound at 2 waves/SIMD — keep independent sincos), packed fp32 math.
// Output: slot r of thread t holds bin k = (t>>3) + 32*br5(r) + 1024*br3(t&7).
__device__ __forceinline__ void big_fftp(cpx* v, cpx* lds, int t, int j, int row)
{
    fft32p(v);
    const float base1 = -7.669903939428206e-4f * (float)t;   // -2pi/8192 * t
    #pragma unroll
    for (int r = 0; r < 32; ++r) {
        const int k1 = br5(r);
        if (k1) {
            float c, s; __sincosf(base1 * (float)k1, &s, &c);
            cpx w; w.x = c; w.y = s;
            cpx o; CMUL(o, v[r], w);
            v[r] = o;
        }
    }
    __syncthreads();
    #pragma unroll
    for (int r = 0; r < 32; ++r) {
        int a = (br5(r) << 8) + t;
        lds[a ^ (((a >> 8) & 7) << 3)] = v[r];
    }
    __syncthreads();
    #pragma unroll
    for (int m1 = 0; m1 < 32; ++m1) {
        int a = (row << 8) + (m1 << 3) + j;
        v[m1] = lds[a ^ (((a >> 8) & 7) << 3)];
    }

    fft32p(v);
    const float base2 = -0.02454369260617026f * (float)j;     // -2pi/256 * j
    #pragma unroll
    for (int r = 0; r < 32; ++r) {
        const int k1p = br5(r);
        if (k1p) {
            float c, s; __sincosf(base2 * (float)k1p, &s, &c);
            cpx w; w.x = c; w.y = s;
            cpx o; CMUL(o, v[r], w);
            v[r] = o;
        }
    }
    // cross-lane FFT_8 over j (DIF; output lane j holds bin br3(j))
    const float R2v = 0.7071067811865475f;
    const int jm = j & 3;
    cpx w1; w1.x = 1.f; w1.y = 0.f;
    if (j >= 4) {
        w1.x = (jm == 0) ? 1.f : (jm == 1) ? R2v : (jm == 2) ? 0.f : -R2v;
        w1.y = (jm == 0) ? 0.f : (jm == 1) ? -R2v : (jm == 2) ? -1.f : -R2v;
    }
    cpx sg1; sg1.x = sg1.y = (j < 4) ? 1.f : -1.f;
    cpx sg2; sg2.x = sg2.y = (j & 2) ? -1.f : 1.f;
    const bool tw2 = (j & 2) && (j & 1);
    cpx w2; w2.x = tw2 ? 0.f : 1.f; w2.y = tw2 ? -1.f : 0.f;
    cpx sg3; sg3.x = sg3.y = (j & 1) ? -1.f : 1.f;
    #pragma unroll
    for (int r = 0; r < 32; ++r) {
        cpx o, sres, tres;
        o.x = __shfl_xor(v[r].x, 4);
        o.y = __shfl_xor(v[r].y, 4);
        CFMA(sres, sg1, v[r], o);      // s = sg1*v + partner
        CMUL(tres, sres, w1);
        o.x = __shfl_xor(tres.x, 2);
        o.y = __shfl_xor(tres.y, 2);
        CFMA(sres, sg2, tres, o);
        CMUL(tres, sres, w2);
        o.x = __shfl_xor(tres.x, 1);
        o.y = __shfl_xor(tres.y, 1);
        CFMA(sres, sg3, tres, o);
        v[r] = sres;
    }
}

// ---------------------------------------------------------------------------
// Kernel 1: Hilbert via register FFT (packed fp32); f16-plane output.
// __launch_bounds__(256) with NO second arg: min-waves w makes the compiler
// budget VGPRs as 256/w — (256,2) capped at 128 and (256,3) at 84, spilling
// the register arrays to scratch (+260..500 MB HBM, R4/R5). Do not add a
// 2nd arg.
// ---------------------------------------------------------------------------
__global__ __launch_bounds__(256) void fft_hilbert_kernel(
    const float* __restrict__ x, _Float16* __restrict__ zr,
    _Float16* __restrict__ zi)
{
    __shared__ cpx lds[8192];   // 64 KB
    const int sig = blockIdx.x;
    const int t = threadIdx.x;
    const int j = t & 7, row = t >> 3;
    const int br3j = ((j & 1) << 2) | (j & 2) | ((j & 4) >> 2);

    cpx v[32];
    const float* xp = x + (size_t)sig * T_LEN;
    #pragma unroll
    for (int n1 = 0; n1 < 32; ++n1) { v[n1].x = xp[(n1 << 8) + t]; v[n1].y = 0.f; }

    big_fftp(v, lds, t, j, row);

    // conj + Hilbert filter
    #pragma unroll
    for (int r = 0; r < 32; ++r) {
        const int k = row + (br5(r) << 5) + (br3j << 10);
        const float h = (k == 0 || k == 4096) ? 1.f : (k < 4096 ? 2.f : 0.f);
        v[r].x = v[r].x * h;
        v[r].y = -v[r].y * h;
    }

    // redistribute to natural order (single pass)
    __syncthreads();
    #pragma unroll
    for (int r = 0; r < 32; ++r) {
        int a = row + (br5(r) << 5) + (br3j << 10);
        lds[a ^ (((a >> 10) & 7) << 3)] = v[r];
    }
    __syncthreads();
    #pragma unroll
    for (int n1 = 0; n1 < 32; ++n1) {
        int a = (n1 << 8) + t;
        v[n1] = lds[a ^ (((a >> 10) & 7) << 3)];
    }

    big_fftp(v, lds, t, j, row);

    // conj + normalize; store f16 planes (fixed t-permutation, PLV-invariant)
    _Float16* zrp = zr + (size_t)sig * T_LEN;
    _Float16* zip = zi + (size_t)sig * T_LEN;
    #pragma unroll
    for (int r = 0; r < 32; ++r) {
        float ar = v[r].x, ai = -v[r].y;
        float inv = rsqrtf(ar * ar + ai * ai);
        zrp[(r << 8) + t] = (_Float16)(ar * inv);
        zip[(r << 8) + t] = (_Float16)(ai * inv);
    }
}

// ---------------------------------------------------------------------------
// Kernel 2: Gram via f16 MFMA, software-pipelined staging (unchanged).
// ---------------------------------------------------------------------------
#define GS 72   // LDS row stride in f16 (64 + 8 pad)
__global__ __launch_bounds__(256) void gram_kernel(
    const _Float16* __restrict__ zr, const _Float16* __restrict__ zi,
    float* __restrict__ part)
{
    __shared__ _Float16 ReS[64 * GS];
    __shared__ _Float16 ImS[64 * GS];
    const int b = blockIdx.x, sl = blockIdx.y, tid = threadIdx.x;
    const int w = tid >> 6, lane = tid & 63;
    const int mrow = lane & 15, quad = lane >> 4;

    f32x4 acc_re[4], acc_i1[4], acc_i2[4];
    #pragma unroll
    for (int tn = 0; tn < 4; ++tn) {
        acc_re[tn] = (f32x4)0.f; acc_i1[tn] = (f32x4)0.f; acc_i2[tn] = (f32x4)0.f;
    }

    const int k0 = sl * (T_LEN / NS_G);
    const int r0 = tid >> 3, r1 = r0 + 32;
    const int c8 = (tid & 7) * 8;
    const size_t gb = (size_t)b * 64 * T_LEN + k0;

    uint4 pr0 = *(const uint4*)&zr[gb + (size_t)r0 * T_LEN + c8];
    uint4 pi0 = *(const uint4*)&zi[gb + (size_t)r0 * T_LEN + c8];
    uint4 pr1 = *(const uint4*)&zr[gb + (size_t)r1 * T_LEN + c8];
    uint4 pi1 = *(const uint4*)&zi[gb + (size_t)r1 * T_LEN + c8];

    const int NCH = (T_LEN / NS_G) / 64;
    for (int chunk = 0; chunk < NCH; ++chunk) {
        __syncthreads();
        *(uint4*)&ReS[r0 * GS + c8] = pr0;
        *(uint4*)&ImS[r0 * GS + c8] = pi0;
        *(uint4*)&ReS[r1 * GS + c8] = pr1;
        *(uint4*)&ImS[r1 * GS + c8] = pi1;
        __syncthreads();
        if (chunk + 1 < NCH) {
            const size_t gn = gb + (chunk + 1) * 64;
            pr0 = *(const uint4*)&zr[gn + (size_t)r0 * T_LEN + c8];
            pi0 = *(const uint4*)&zi[gn + (size_t)r0 * T_LEN + c8];
            pr1 = *(const uint4*)&zr[gn + (size_t)r1 * T_LEN + c8];
            pi1 = *(const uint4*)&zi[gn + (size_t)r1 * T_LEN + c8];
        }
        #pragma unroll
        for (int ks = 0; ks < 2; ++ks) {
            const int koff = ks * 32 + quad * 8;
            f16x8 a_re = *(f16x8*)&ReS[(w * 16 + mrow) * GS + koff];
            f16x8 a_im = *(f16x8*)&ImS[(w * 16 + mrow) * GS + koff];
            #pragma unroll
            for (int tn = 0; tn < 4; ++tn) {
                f16x8 b_re = *(f16x8*)&ReS[(tn * 16 + mrow) * GS + koff];
                f16x8 b_im = *(f16x8*)&ImS[(tn * 16 + mrow) * GS + koff];
                acc_re[tn] = __builtin_amdgcn_mfma_f32_16x16x32_f16(a_re, b_re, acc_re[tn], 0, 0, 0);
                acc_re[tn] = __builtin_amdgcn_mfma_f32_16x16x32_f16(a_im, b_im, acc_re[tn], 0, 0, 0);
                acc_i1[tn] = __builtin_amdgcn_mfma_f32_16x16x32_f16(a_im, b_re, acc_i1[tn], 0, 0, 0);
                acc_i2[tn] = __builtin_amdgcn_mfma_f32_16x16x32_f16(a_re, b_im, acc_i2[tn], 0, 0, 0);
            }
        }
    }

    float2* pp = (float2*)part + (size_t)(b * NS_G + sl) * 4096;
    #pragma unroll
    for (int tn = 0; tn < 4; ++tn)
        #pragma unroll
        for (int reg = 0; reg < 4; ++reg) {
            int m = w * 16 + quad * 4 + reg;
            int n = tn * 16 + mrow;
            float2 vv;
            vv.x = acc_re[tn][reg];
            vv.y = acc_i1[tn][reg] - acc_i2[tn][reg];
            pp[m * 64 + n] = vv;
        }
}

// ---------------------------------------------------------------------------
// Kernel 3: PLV-reduce + GCN + MHA (unchanged)
// ---------------------------------------------------------------------------
__global__ __launch_bounds__(1024) void gnn_mha_kernel(
    const float* __restrict__ part, const float* __restrict__ emb,
    const float* __restrict__ w1,   const float* __restrict__ b1,
    const float* __restrict__ w2,   const float* __restrict__ b2,
    const float* __restrict__ ipw,  const float* __restrict__ ipb,
    const float* __restrict__ opw,  const float* __restrict__ opb,
    float* __restrict__ out0, float* __restrict__ out1,
    float* __restrict__ out2)
{
    __shared__ float S[16384];
    const int b = blockIdx.x, tid = threadIdx.x;
    const int lane = tid & 63, w = tid >> 6;
    const int i0 = w * 4;

    const float2* pf = (const float2*)part;
    for (int e = tid; e < 4096; e += 1024) {
        float gr = 0.f, gi = 0.f;
        #pragma unroll
        for (int s = 0; s < NS_G; ++s) {
            float2 vv = pf[(size_t)(b * NS_G + s) * 4096 + e];
            gr += vv.x; gi += vv.y;
        }
        int i = e >> 6, jj = e & 63;
        float val = (i == jj) ? 0.f
                              : sqrtf(gr * gr + gi * gi) * (1.0f / 8192.0f);
        S[e] = val;
        out0[(size_t)b * 4096 + e] = val;
    }
    __syncthreads();

    {   // M = conn @ emb
        float acc[4] = {0.f, 0.f, 0.f, 0.f};
        #pragma unroll 8
        for (int k = 0; k < 64; ++k) {
            float ev = emb[k * 64 + lane];
            #pragma unroll
            for (int r = 0; r < 4; ++r)
                acc[r] = fmaf(S[(i0 + r) * 64 + k], ev, acc[r]);
        }
        #pragma unroll
        for (int r = 0; r < 4; ++r) S[4096 + (i0 + r) * 64 + lane] = acc[r];
    }
    __syncthreads();

    {   // h1 = relu(M @ w1 + b1)
        float a0[4] = {0.f, 0.f, 0.f, 0.f}, a1[4] = {0.f, 0.f, 0.f, 0.f};
        #pragma unroll 8
        for (int k = 0; k < 64; ++k) {
            float wa = w1[k * 128 + lane];
            float wb = w1[k * 128 + 64 + lane];
            #pragma unroll
            for (int r = 0; r < 4; ++r) {
                float m = S[4096 + (i0 + r) * 64 + k];
                a0[r] = fmaf(m, wa, a0[r]);
                a1[r] = fmaf(m, wb, a1[r]);
            }
        }
        float bb0 = b1[lane], bb1 = b1[64 + lane];
        #pragma unroll
        for (int r = 0; r < 4; ++r) {
            S[8192 + (i0 + r) * 128 + lane]      = fmaxf(a0[r] + bb0, 0.f);
            S[8192 + (i0 + r) * 128 + 64 + lane] = fmaxf(a1[r] + bb1, 0.f);
        }
    }
    __syncthreads();

    {   // P = h1 @ w2
        float acc[4] = {0.f, 0.f, 0.f, 0.f};
        #pragma unroll 8
        for (int c = 0; c < 128; ++c) {
            float wv = w2[c * 64 + lane];
            #pragma unroll
            for (int r = 0; r < 4; ++r)
                acc[r] = fmaf(S[8192 + (i0 + r) * 128 + c], wv, acc[r]);
        }
        __syncthreads();
        #pragma unroll
        for (int r = 0; r < 4; ++r) S[4096 + (i0 + r) * 64 + lane] = acc[r];
    }
    __syncthreads();

    {   // h2 = conn @ P + b2 (in-place over conn rows)
        float acc[4] = {0.f, 0.f, 0.f, 0.f};
        #pragma unroll 8
        for (int k = 0; k < 64; ++k) {
            float pv = S[4096 + k * 64 + lane];
            #pragma unroll
            for (int r = 0; r < 4; ++r)
                acc[r] = fmaf(S[(i0 + r) * 64 + k], pv, acc[r]);
        }
        float bb = b2[lane];
        #pragma unroll
        for (int r = 0; r < 4; ++r) {
            float vv = acc[r] + bb;
            S[(i0 + r) * 64 + lane] = vv;
            out2[(size_t)b * 4096 + (i0 + r) * 64 + lane] = vv;
        }
    }
    __syncthreads();

    {   // qkv
        float aq[4] = {0.f, 0.f, 0.f, 0.f};
        float ak[4] = {0.f, 0.f, 0.f, 0.f};
        float av[4] = {0.f, 0.f, 0.f, 0.f};
        #pragma unroll 8
        for (int k = 0; k < 64; ++k) {
            float wq = ipw[lane * 64 + k];
            float wk = ipw[(64 + lane) * 64 + k];
            float wv = ipw[(128 + lane) * 64 + k];
            #pragma unroll
            for (int r = 0; r < 4; ++r) {
                float hv = S[(i0 + r) * 64 + k];
                aq[r] = fmaf(hv, wq, aq[r]);
                ak[r] = fmaf(hv, wk, ak[r]);
                av[r] = fmaf(hv, wv, av[r]);
            }
        }
        float bq = ipb[lane], bk = ipb[64 + lane], bv = ipb[128 + lane];
        __syncthreads();
        #pragma unroll
        for (int r = 0; r < 4; ++r) {
            S[4096  + (i0 + r) * 64 + lane] = aq[r] + bq;
            S[8192  + (i0 + r) * 64 + lane] = ak[r] + bk;
            S[12288 + (i0 + r) * 64 + lane] = av[r] + bv;
        }
    }
    __syncthreads();

    const int h = w >> 1;
    float kk[8];
    #pragma unroll
    for (int d = 0; d < 8; ++d) kk[d] = S[8192 + lane * 64 + h * 8 + d];
    __syncthreads();

    {   // scores + softmax + attn@V
        const float iscale = 0.35355339059327373f;
        const int mc = lane >> 3, dd = lane & 7;
        for (int rr = 0; rr < 32; ++rr) {
            const int n = (w & 1) * 32 + rr;
            float s = 0.f;
            #pragma unroll
            for (int d = 0; d < 8; ++d)
                s = fmaf(S[4096 + n * 64 + h * 8 + d], kk[d], s);
            s *= iscale;
            float mx = s;
            #pragma unroll
            for (int off = 1; off < 64; off <<= 1)
                mx = fmaxf(mx, __shfl_xor(mx, off));
            float ev = __expf(s - mx);
            float sum = ev;
            #pragma unroll
            for (int off = 1; off < 64; off <<= 1)
                sum += __shfl_xor(sum, off);
            S[8192 + w * 68 + lane] = ev / sum;
            float o = 0.f;
            #pragma unroll
            for (int jx = 0; jx < 8; ++jx)
                o = fmaf(S[8192 + w * 68 + mc * 8 + jx],
                         S[12288 + (mc * 8 + jx) * 64 + h * 8 + dd], o);
            o += __shfl_xor(o, 8);
            o += __shfl_xor(o, 16);
            o += __shfl_xor(o, 32);
            if (lane < 8) S[n * 64 + h * 8 + lane] = o;
        }
    }
    __syncthreads();

    for (int e = tid; e < 4096; e += 1024) {
        int r = e >> 6, c = e & 63;
        S[8192 + r * 65 + c] = opw[e];
    }
    __syncthreads();

    {   // out1 = oh @ opw^T + opb
        float acc[4] = {0.f, 0.f, 0.f, 0.f};
        #pragma unroll 8
        for (int c = 0; c < 64; ++c) {
            float wv = S[8192 + lane * 65 + c];
            #pragma unroll
            for (int r = 0; r < 4; ++r)
                acc[r] = fmaf(S[(i0 + r) * 64 + c], wv, acc[r]);
        }
        float ob = opb[lane];
        #pragma unroll
        for (int r = 0; r < 4; ++r)
            out1[(size_t)b * 4096 + (i0 + r) * 64 + lane] = acc[r] + ob;
    }
}

// ---------------------------------------------------------------------------
extern "C" void kernel_launch(void* const* d_in, const int* in_sizes, int n_in,
                              void* d_out, int out_size, void* d_ws, size_t ws_size,
                              hipStream_t stream)
{
    const float* x   = (const float*)d_in[0];
    const float* emb = (const float*)d_in[1];
    const float* w1  = (const float*)d_in[2];
    const float* b1  = (const float*)d_in[3];
    const float* w2  = (const float*)d_in[4];
    const float* b2  = (const float*)d_in[5];
    const float* ipw = (const float*)d_in[6];
    const float* ipb = (const float*)d_in[7];
    const float* opw = (const float*)d_in[8];
    const float* opb = (const float*)d_in[9];

    float* out  = (float*)d_out;
    float* out0 = out;
    float* out1 = out + 131072;
    float* out2 = out + 262144;

    _Float16* zr = (_Float16*)d_ws;                     // 32 MB
    _Float16* zi = zr + (size_t)2048 * T_LEN;           // 32 MB
    float* part  = (float*)(zi + (size_t)2048 * T_LEN); // 8 MB

    hipLaunchKernelGGL(fft_hilbert_kernel, dim3(32 * 64), dim3(256), 0, stream,
                       x, zr, zi);
    hipLaunchKernelGGL(gram_kernel, dim3(32, NS_G), dim3(256), 0, stream,
                       zr, zi, part);
    hipLaunchKernelGGL(gnn_mha_kernel, dim3(32), dim3(1024), 0, stream,
                       part, emb, w1, b1, w2, b2, ipw, ipb, opw, opb,
                       out0, out1, out2);
}